// Round 10
// baseline (354.606 us; speedup 1.0000x reference)
//
#include <hip/hip_runtime.h>
#include <hip/hip_bf16.h>
#include <math.h>

// Problem constants
#define B_ 8
#define S_ 4096
#define E_ 1024
#define H_ 128
#define MIN_K 32
// d_out layout: filtered [B,S,E] | selection_mask [B,S] | expected_k [B]
#define OUT_MASK_OFF (B_*S_*E_)
#define OUT_EK_OFF   (B_*S_*E_ + B_*S_)

// workspace byte offsets (total 917,536 B)
#define LOGITS_OFF 0
#define SOFT_OFF   131072
#define CNT_OFF    262144
#define KROW_OFF   393216
#define WB_OFF     393248   // 16B aligned; 512 KB tiled split-bf16 weights

typedef __attribute__((ext_vector_type(8))) short   frag8;   // 8 bf16 (4 VGPR)
typedef __attribute__((ext_vector_type(4))) float   fragc;   // 4 f32 acc

static __device__ __forceinline__ unsigned short bf16_rne(float f) {
  unsigned u = __float_as_uint(f);
  unsigned r = u + 0x7FFF + ((u >> 16) & 1);
  return (unsigned short)(r >> 16);
}
static __device__ __forceinline__ float bf16_to_f32(unsigned short h) {
  return __uint_as_float(((unsigned)h) << 16);
}

// ---------------------------------------------------------------------------
// Prep: w1 [E][H] f32 -> wb tiled split-bf16:
//   wb[t][plane][n][k']  t=k-tile (32 tiles of KT=32), plane 0=hi 1=lo,
//   n=0..127, k'=0..31.  A B-fragment load (lane: n=l15+16nt, k'=quad*8) is
//   16 consecutive fully-consumed 64B lines — zero-waste coalescing.
// ---------------------------------------------------------------------------
__global__ __launch_bounds__(256) void prep_w_kernel(
    const float* __restrict__ w1, unsigned short* __restrict__ wb)
{
  int id = blockIdx.x * 256 + threadIdx.x;       // 0..32767
  int k  = id >> 5;                               // 0..1023
  int n4 = id & 31;                               // 0..31
  float4 w = *(const float4*)(w1 + k * H_ + n4 * 4);
  int t  = k >> 5;          // k-tile
  int kp = k & 31;          // k'
#pragma unroll
  for (int e = 0; e < 4; ++e) {
    float f = (e == 0) ? w.x : (e == 1) ? w.y : (e == 2) ? w.z : w.w;
    unsigned short hi = bf16_rne(f);
    unsigned short lo = bf16_rne(f - bf16_to_f32(hi));
    int n = n4 * 4 + e;
    wb[t * 8192 +        n * 32 + kp] = hi;   // plane 0
    wb[t * 8192 + 4096 + n * 32 + kp] = lo;   // plane 1
  }
}

// ---------------------------------------------------------------------------
// Scorer v9: ZERO-BARRIER wave-independent K-loop. v1..v8 post-mortem: every
// structure kept block-wide barriers coupling the waves; all landed 67-78 us
// regardless of staging pattern — the phase wall is barrier convergence, not
// load counters (v7: raw barriers = no change) nor blocks/CU (v8: +3 us).
// Fix: decompose per WAVE. Wave owns 16 rows x all 128 cols (acc[8],
// 24 MFMA/step as before):
//  * A: wave-PRIVATE LDS region (own 16 rows, depth-2 reg pipeline S0/S1).
//    Same-wave ds_write->ds_read is ordered by lgkmcnt (compiler-emitted);
//    NO __syncthreads anywhere in the K-loop.
//  * B: direct fragment loads from wb (no LDS) — all 8 waves/CU read the
//    same 16 KB step-tile => L1-resident (32 KB L1 = 2 tiles); per-CU L2
//    traffic hits the 1 MB floor (512 KB A + 512 KB B).
//  * Waves slip freely across K-steps: m114 cross-wave overlap with no
//    barrier to re-converge at.
// 256 thr (4 waves) x grid 512 = 8 waves/CU. Epilogue: lane holds all nt ->
// sum nt 0..7 ascending, 16-lane butterfly, direct store (no part LDS).
// ---------------------------------------------------------------------------
#define KT 32
#define NTILES (E_ / KT)
#define AS 36   // A LDS stride in floats (144 B: 16B-aligned, 2-way banks = free)

__global__ __launch_bounds__(256, 2) void scorer_kernel(
    const float* __restrict__ x,
    const unsigned short* __restrict__ wb,
    const float* __restrict__ b1, const float* __restrict__ w2,
    const float* __restrict__ b2, float* __restrict__ logits)
{
  __shared__ float as_f[2][4][16 * AS];   // [buf][wave][row*AS] = 18,432 B

  const int tid  = threadIdx.x;
  const int wv   = tid >> 6;
  const int lane = tid & 63;
  const int l15  = lane & 15;
  const int quad = lane >> 4;
  const int m0   = blockIdx.x * 64 + wv * 16;   // wave's 16 rows

  // A staging map (within wave): lane -> (row r=lane>>2, part p=lane&3).
  const int r = lane >> 2, p = lane & 3;
  const float* __restrict__ xsrc = x + (size_t)(m0 + r) * E_ + p * 8;
  const int aoff = r * AS + p * 8;
  const int foff = l15 * AS + quad * 8;

  // B fragment base: lane offset within a step-tile (n=l15[+16nt], k'=quad*8)
  const unsigned short* __restrict__ bb = wb + l15 * 32 + quad * 8;

  fragc acc[8];
#pragma unroll
  for (int nt = 0; nt < 8; ++nt) acc[nt] = (fragc)(0.f);

  // depth-2 A pipeline: named register sets (static, never runtime-indexed)
  float4 a0_S0, a1_S0, a0_S1, a1_S1;

#define A_COMPUTE_STEP(BUF, T) {                                              \
    float4 f0_ = *(const float4*)&as_f[BUF][wv][foff];                        \
    float4 f1_ = *(const float4*)&as_f[BUF][wv][foff + 4];                    \
    frag8 ah, al;                                                             \
    { float ff_[8] = {f0_.x, f0_.y, f0_.z, f0_.w, f1_.x, f1_.y, f1_.z, f1_.w};\
      _Pragma("unroll") for (int e = 0; e < 8; ++e) {                         \
        unsigned short hi_ = bf16_rne(ff_[e]);                                \
        ah[e] = (short)hi_;                                                   \
        al[e] = (short)bf16_rne(ff_[e] - bf16_to_f32(hi_)); } }               \
    const unsigned short* bth_ = bb + (T) * 8192;                             \
    const unsigned short* btl_ = bth_ + 4096;                                 \
    _Pragma("unroll") for (int nt = 0; nt < 8; ++nt) {                        \
      frag8 bh_ = *(const frag8*)(bth_ + nt * 512);                           \
      frag8 bl_ = *(const frag8*)(btl_ + nt * 512);                           \
      acc[nt] = __builtin_amdgcn_mfma_f32_16x16x32_bf16(ah, bh_, acc[nt], 0, 0, 0); \
      acc[nt] = __builtin_amdgcn_mfma_f32_16x16x32_bf16(ah, bl_, acc[nt], 0, 0, 0); \
      acc[nt] = __builtin_amdgcn_mfma_f32_16x16x32_bf16(al, bh_, acc[nt], 0, 0, 0); } }

  // prologue: S0 <- tile0, S1 <- tile1, write S0 -> buf0
  a0_S0 = *(const float4*)(xsrc);          a1_S0 = *(const float4*)(xsrc + 4);
  a0_S1 = *(const float4*)(xsrc + KT);     a1_S1 = *(const float4*)(xsrc + KT + 4);
  *(float4*)&as_f[0][wv][aoff] = a0_S0;    *(float4*)&as_f[0][wv][aoff + 4] = a1_S0;

#pragma unroll 1
  for (int tp = 0; tp < 16; ++tp) {
    // EVEN: compute 2tp from buf0; S1 holds 2tp+1; issue S0 <- 2tp+2
    {
      const int t = 2 * tp;
      if (t + 2 < NTILES) {
        a0_S0 = *(const float4*)(xsrc + (t + 2) * KT);
        a1_S0 = *(const float4*)(xsrc + (t + 2) * KT + 4);
      }
      A_COMPUTE_STEP(0, t)
      // write t+1 (regs loaded a full step ago -> counted vmcnt, no drain)
      *(float4*)&as_f[1][wv][aoff] = a0_S1;
      *(float4*)&as_f[1][wv][aoff + 4] = a1_S1;
    }
    // ODD: compute 2tp+1 from buf1; S0 holds 2tp+2; issue S1 <- 2tp+3
    {
      const int t = 2 * tp + 1;
      if (t + 2 < NTILES) {
        a0_S1 = *(const float4*)(xsrc + (t + 2) * KT);
        a1_S1 = *(const float4*)(xsrc + (t + 2) * KT + 4);
      }
      A_COMPUTE_STEP(1, t)
      if (tp < 15) {
        *(float4*)&as_f[0][wv][aoff] = a0_S0;
        *(float4*)&as_f[0][wv][aoff + 4] = a1_S0;
      }
    }
  }

  // Epilogue: lane holds rows quad*4+reg, n = nt*16+l15 (all 8 nt).
  // p = sum_nt relu(acc+b1)*w2 (ascending fmaf); butterfly over 16 lanes (n);
  // direct store — no shared memory, no barrier.
  float b1v[8], w2v[8];
#pragma unroll
  for (int nt = 0; nt < 8; ++nt) {
    b1v[nt] = b1[nt * 16 + l15];
    w2v[nt] = w2[nt * 16 + l15];
  }
  float pv[4];
#pragma unroll
  for (int reg = 0; reg < 4; ++reg) {
    float pacc = 0.f;
#pragma unroll
    for (int nt = 0; nt < 8; ++nt) {
      float h = acc[nt][reg] + b1v[nt];
      h = h > 0.f ? h : 0.f;
      pacc = fmaf(h, w2v[nt], pacc);
    }
    pv[reg] = pacc;
  }
#pragma unroll
  for (int mask = 1; mask < 16; mask <<= 1)
#pragma unroll
    for (int reg = 0; reg < 4; ++reg)
      pv[reg] += __shfl_xor(pv[reg], mask);

  if (l15 == 0) {
#pragma unroll
    for (int reg = 0; reg < 4; ++reg)
      logits[m0 + quad * 4 + reg] = pv[reg] + b2[0];
  }
#undef A_COMPUTE_STEP
}

// ---------------------------------------------------------------------------
// Row kernel: expected_k, k, gumbel, softmax. grid=8, block=1024. (unchanged)
// ---------------------------------------------------------------------------
__global__ __launch_bounds__(1024) void row_kernel(
    const float* __restrict__ logits, const float* __restrict__ u,
    float* __restrict__ soft, int* __restrict__ krow, float* __restrict__ ek_out)
{
  const int b = blockIdx.x;
  const int t = threadIdx.x;
  const float* Lrow = logits + b * S_;
  const float* urow = u + b * S_;

  __shared__ double red[1024];
  __shared__ float  redf[1024];

  float z[4];
  double psig = 0.0;
  float zmax = -INFINITY;
#pragma unroll
  for (int i = 0; i < 4; ++i) {
    int j = t + i * 1024;
    float L = Lrow[j];
    float g = -logf(-logf(urow[j]));
    z[i] = L + g;
    psig += (double)(1.f / (1.f + expf(-L)));
    zmax = fmaxf(zmax, z[i]);
  }
  red[t] = psig; redf[t] = zmax;
  __syncthreads();
  for (int s2 = 512; s2 > 0; s2 >>= 1) {
    if (t < s2) { red[t] += red[t + s2]; redf[t] = fmaxf(redf[t], redf[t + s2]); }
    __syncthreads();
  }
  __shared__ float m_sh; __shared__ double ek_sh;
  if (t == 0) { m_sh = redf[0]; ek_sh = red[0]; }
  __syncthreads();
  float m = m_sh;

  float e[4];
  double pexp = 0.0;
#pragma unroll
  for (int i = 0; i < 4; ++i) { e[i] = expf(z[i] - m); pexp += (double)e[i]; }
  red[t] = pexp;
  __syncthreads();
  for (int s2 = 512; s2 > 0; s2 >>= 1) {
    if (t < s2) red[t] += red[t + s2];
    __syncthreads();
  }
  __shared__ float den_sh;
  if (t == 0) den_sh = (float)red[0];
  __syncthreads();
  float den = den_sh;
#pragma unroll
  for (int i = 0; i < 4; ++i) soft[b * S_ + t + i * 1024] = e[i] / den;

  if (t == 0) {
    float ekf = (float)ek_sh;
    int k = (int)ekf;
    if (k < MIN_K) k = MIN_K;
    krow[b] = k;
    ek_out[b] = ekf;
  }
}

// ---------------------------------------------------------------------------
// Rank partial: grid (16 i-chunks, 4 j-chunks, 8 rows). Integer atomicAdd
// (deterministic). j-chunk staged in LDS; all lanes read same addr (broadcast).
// ---------------------------------------------------------------------------
__global__ __launch_bounds__(256) void rank_kernel(
    const float* __restrict__ soft, int* __restrict__ counts)
{
  __shared__ float4 sjs[256];
  const int b  = blockIdx.z;
  const int ic = blockIdx.x;
  const int jc = blockIdx.y;
  const int tid = threadIdx.x;
  const float* row = soft + b * S_;

  sjs[tid] = ((const float4*)row)[jc * 256 + tid];
  const int i = ic * 256 + tid;
  const float si = row[i];
  __syncthreads();

  int cnt = 0;
  const int jbase = jc * 1024;
  for (int j4 = 0; j4 < 256; ++j4) {
    float4 vv = sjs[j4];
    int j = jbase + j4 * 4;
    cnt += (vv.x > si) || (vv.x == si && (j + 0) < i);
    cnt += (vv.y > si) || (vv.y == si && (j + 1) < i);
    cnt += (vv.z > si) || (vv.z == si && (j + 2) < i);
    cnt += (vv.w > si) || (vv.w == si && (j + 3) < i);
  }
  atomicAdd(&counts[b * S_ + i], cnt);
}

// ---------------------------------------------------------------------------
// Filter + mask finalize: one block per token (1024 floats). Uniform scalar
// loads of cnt/k/soft; thread 0 writes selection_mask.
// ---------------------------------------------------------------------------
__global__ __launch_bounds__(256) void filter_kernel(
    const float* __restrict__ x, const float* __restrict__ soft,
    const int* __restrict__ counts, const int* __restrict__ krow,
    float* __restrict__ out, float* __restrict__ mask_out)
{
  const int token = blockIdx.x;           // 0..32767
  const int b = token >> 12;              // S_=4096
  const float s = soft[token];
  const float h = (counts[token] < krow[b]) ? 1.f : 0.f;
  const float sel = (h - s) + s;

  size_t base = (size_t)token * (E_ / 4) + threadIdx.x;
  float4 v = ((const float4*)x)[base];
  v.x *= sel; v.y *= sel; v.z *= sel; v.w *= sel;
  ((float4*)out)[base] = v;
  if (threadIdx.x == 0) mask_out[token] = sel;
}

// ---------------------------------------------------------------------------
extern "C" void kernel_launch(void* const* d_in, const int* in_sizes, int n_in,
                              void* d_out, int out_size, void* d_ws, size_t ws_size,
                              hipStream_t stream) {
  const float* x  = (const float*)d_in[0];
  const float* w1 = (const float*)d_in[1];
  const float* b1 = (const float*)d_in[2];
  const float* w2 = (const float*)d_in[3];
  const float* b2 = (const float*)d_in[4];
  const float* u  = (const float*)d_in[5];

  float* out = (float*)d_out;
  float* out_filt = out;
  float* out_mask = out + OUT_MASK_OFF;
  float* out_ek   = out + OUT_EK_OFF;

  char* ws = (char*)d_ws;
  float*          ws_logits = (float*)(ws + LOGITS_OFF);
  float*          ws_soft   = (float*)(ws + SOFT_OFF);
  int*            ws_cnt    = (int*)(ws + CNT_OFF);
  int*            ws_krow   = (int*)(ws + KROW_OFF);
  unsigned short* ws_wb     = (unsigned short*)(ws + WB_OFF);

  hipMemsetAsync(ws_cnt, 0, B_ * S_ * sizeof(int), stream);
  prep_w_kernel<<<dim3(128), dim3(256), 0, stream>>>(w1, ws_wb);
  scorer_kernel<<<dim3(B_ * S_ / 64), dim3(256), 0, stream>>>(
      x, ws_wb, b1, w2, b2, ws_logits);
  row_kernel<<<dim3(B_), dim3(1024), 0, stream>>>(ws_logits, u, ws_soft, ws_krow, out_ek);
  rank_kernel<<<dim3(16, 4, 8), dim3(256), 0, stream>>>(ws_soft, ws_cnt);
  filter_kernel<<<dim3(B_ * S_), dim3(256), 0, stream>>>(
      x, ws_soft, ws_cnt, ws_krow, out_filt, out_mask);
}

// Round 11
// 314.273 us; speedup vs baseline: 1.1283x; 1.1283x over previous
//
#include <hip/hip_runtime.h>
#include <hip/hip_bf16.h>
#include <math.h>

// Problem constants
#define B_ 8
#define S_ 4096
#define E_ 1024
#define H_ 128
#define MIN_K 32
// d_out layout: filtered [B,S,E] | selection_mask [B,S] | expected_k [B]
#define OUT_MASK_OFF (B_*S_*E_)
#define OUT_EK_OFF   (B_*S_*E_ + B_*S_)

// workspace byte offsets (total 917,536 B)
#define LOGITS_OFF 0
#define SOFT_OFF   131072
#define CNT_OFF    262144
#define KROW_OFF   393216
#define WB_OFF     393248   // 16B aligned; 512 KB tiled split-bf16 weights

typedef __attribute__((ext_vector_type(8))) short   frag8;   // 8 bf16 (4 VGPR)
typedef __attribute__((ext_vector_type(4))) float   fragc;   // 4 f32 acc

static __device__ __forceinline__ unsigned short bf16_rne(float f) {
  unsigned u = __float_as_uint(f);
  unsigned r = u + 0x7FFF + ((u >> 16) & 1);
  return (unsigned short)(r >> 16);
}
static __device__ __forceinline__ float bf16_to_f32(unsigned short h) {
  return __uint_as_float(((unsigned)h) << 16);
}

// ---------------------------------------------------------------------------
// Prep: w1 [E][H] f32 -> wb tiled split-bf16:
//   wb[t][plane][n][k']  t=k-tile (32 tiles of KT=32), plane 0=hi 1=lo,
//   n=0..127, k'=0..31.  A B-fragment load (lane: n=l15+16nt, k'=quad*8) is
//   16 consecutive fully-consumed 64B lines — zero-waste coalescing.
// ---------------------------------------------------------------------------
__global__ __launch_bounds__(256) void prep_w_kernel(
    const float* __restrict__ w1, unsigned short* __restrict__ wb)
{
  int id = blockIdx.x * 256 + threadIdx.x;       // 0..32767
  int k  = id >> 5;                               // 0..1023
  int n4 = id & 31;                               // 0..31
  float4 w = *(const float4*)(w1 + k * H_ + n4 * 4);
  int t  = k >> 5;          // k-tile
  int kp = k & 31;          // k'
#pragma unroll
  for (int e = 0; e < 4; ++e) {
    float f = (e == 0) ? w.x : (e == 1) ? w.y : (e == 2) ? w.z : w.w;
    unsigned short hi = bf16_rne(f);
    unsigned short lo = bf16_rne(f - bf16_to_f32(hi));
    int n = n4 * 4 + e;
    wb[t * 8192 +        n * 32 + kp] = hi;   // plane 0
    wb[t * 8192 + 4096 + n * 32 + kp] = lo;   // plane 1
  }
}

// ---------------------------------------------------------------------------
// Scorer v10: SPLIT-K, barrier-free K-loop, fetch-once traffic.
// Nine-round synthesis: scorer needs BOTH (a) fetch-once per-CU traffic
// (v5-v8, 67-73 us; violating it = 110-150 us in v4/v9) and (b) no block-wide
// barrier lockstep (the ~50 us above the ~15 us memory floor is 32 barrier
// phases x worst-wave latency). Split-K gives both with no redundant FLOPs:
//   Block: 256 thr, 4 waves, M=64 rows, grid 512 (2 blocks/CU).
//   Wave (kh=wv&1, ng=wv>>1): PRE-ACTIVATION partial acc for all 64 rows
//   (4 mt) x its 64 n (4 nt) over its k-half (512 k = 16 private steps).
//   A: per-lane direct from x (fully-consumed lines; read 2x/block, L2-hot).
//   B: direct frag loads from wb k-tiles (disjoint across waves; once/block).
//   ZERO barriers and ZERO LDS in the K-loop; 8 waves/CU slip freely (m114).
//   Reduction: kh=1 waves write acc to padded LDS (stride 66: conflict-free),
//   one barrier, kh=0 waves add -> relu is applied AFTER the full-k sum
//   (required: relu nonlinear). Epilogue = v8's exact tree.
// Numerics: one k-sum reassociation (acc_k0..511 + acc_k512..1023) vs v8's
// serial chain — same class as v5's accepted epilogue reassociation.
// ---------------------------------------------------------------------------
#define KT 32
#define RS 66   // reduction LDS stride in floats (264 B -> 2-way banks, free)

__global__ __launch_bounds__(256, 2) void scorer_kernel(
    const float* __restrict__ x,
    const unsigned short* __restrict__ wb,
    const float* __restrict__ b1, const float* __restrict__ w2,
    const float* __restrict__ b2, float* __restrict__ logits)
{
  __shared__ float red[2 * 64 * RS];   // 33,792 B
  __shared__ float part[2][64];

  const int tid  = threadIdx.x;
  const int wv   = tid >> 6;
  const int lane = tid & 63;
  const int l15  = lane & 15;
  const int quad = lane >> 4;
  const int kh   = wv & 1;           // k-half: k in [kh*512, +512)
  const int ng   = wv >> 1;          // n-half: n in [ng*64, +64)
  const int m0   = blockIdx.x * 64;

  // A row pointers (rows m0 + mt*16 + l15, k base kh*512 + quad*8)
  const float* __restrict__ ar0 = x + (size_t)(m0 + 0  + l15) * E_ + kh * 512 + quad * 8;
  const float* __restrict__ ar1 = x + (size_t)(m0 + 16 + l15) * E_ + kh * 512 + quad * 8;
  const float* __restrict__ ar2 = x + (size_t)(m0 + 32 + l15) * E_ + kh * 512 + quad * 8;
  const float* __restrict__ ar3 = x + (size_t)(m0 + 48 + l15) * E_ + kh * 512 + quad * 8;

  // B fragment base: tile T = kh*16 + t at T*8192; nt adds 512 shorts;
  // lane offset (n = ng*64 + nt*16 + l15, k' = quad*8).
  const unsigned short* __restrict__ bb =
      wb + (size_t)kh * 16 * 8192 + (ng * 64 + l15) * 32 + quad * 8;

  fragc acc[4][4];
#pragma unroll
  for (int mt = 0; mt < 4; ++mt)
#pragma unroll
    for (int nt = 0; nt < 4; ++nt)
      acc[mt][nt] = (fragc)(0.f);

#pragma unroll 2
  for (int t = 0; t < 16; ++t) {
    const int ko = t * KT;
    // A: load + split-bf16 convert, 4 m-tiles (same bits as staged path)
    frag8 ah[4], al[4];
    {
      const float* ars[4] = {ar0, ar1, ar2, ar3};
#pragma unroll
      for (int mt = 0; mt < 4; ++mt) {
        float4 f0 = *(const float4*)(ars[mt] + ko);
        float4 f1 = *(const float4*)(ars[mt] + ko + 4);
        float ff[8] = {f0.x, f0.y, f0.z, f0.w, f1.x, f1.y, f1.z, f1.w};
#pragma unroll
        for (int e = 0; e < 8; ++e) {
          unsigned short hi = bf16_rne(ff[e]);
          ah[mt][e] = (short)hi;
          al[mt][e] = (short)bf16_rne(ff[e] - bf16_to_f32(hi));
        }
      }
    }
    // B: 8 zero-waste frag loads (16 consecutive 64B lines each)
    frag8 bh[4], bl[4];
    {
      const unsigned short* bt = bb + t * 8192;
#pragma unroll
      for (int nt = 0; nt < 4; ++nt) {
        bh[nt] = *(const frag8*)(bt + nt * 512);
        bl[nt] = *(const frag8*)(bt + 4096 + nt * 512);
      }
    }
    // 48 MFMAs; per-acc chain order hh, hl, lh; t ascending within k-half
#pragma unroll
    for (int mt = 0; mt < 4; ++mt)
#pragma unroll
      for (int nt = 0; nt < 4; ++nt) {
        acc[mt][nt] = __builtin_amdgcn_mfma_f32_16x16x32_bf16(ah[mt], bh[nt], acc[mt][nt], 0, 0, 0);
        acc[mt][nt] = __builtin_amdgcn_mfma_f32_16x16x32_bf16(ah[mt], bl[nt], acc[mt][nt], 0, 0, 0);
        acc[mt][nt] = __builtin_amdgcn_mfma_f32_16x16x32_bf16(al[mt], bh[nt], acc[mt][nt], 0, 0, 0);
      }
  }

  // ---- k-half reduction (pre-activation) ----
  const int rbase = (ng * 64 + lane) * RS;
  if (kh == 1) {
#pragma unroll
    for (int mt = 0; mt < 4; ++mt)
#pragma unroll
      for (int nt = 0; nt < 4; ++nt)
#pragma unroll
        for (int reg = 0; reg < 4; ++reg)
          red[rbase + mt * 16 + nt * 4 + reg] = acc[mt][nt][reg];
  }
  __syncthreads();

  if (kh == 0) {
#pragma unroll
    for (int mt = 0; mt < 4; ++mt)
#pragma unroll
      for (int nt = 0; nt < 4; ++nt)
#pragma unroll
        for (int reg = 0; reg < 4; ++reg)
          acc[mt][nt][reg] += red[rbase + mt * 16 + nt * 4 + reg];

    // Epilogue (v8's exact tree): h = relu(acc + b1[n]); p = sum_nt h*w2[n]
    // (ascending fmaf); 16-lane butterfly (n); cross ng-groups via part LDS.
    float b1v[4], w2v[4];
#pragma unroll
    for (int nt = 0; nt < 4; ++nt) {
      int n = ng * 64 + nt * 16 + l15;
      b1v[nt] = b1[n]; w2v[nt] = w2[n];
    }
    float v[4][4];
#pragma unroll
    for (int mt = 0; mt < 4; ++mt)
#pragma unroll
      for (int reg = 0; reg < 4; ++reg) {
        float pacc = 0.f;
#pragma unroll
        for (int nt = 0; nt < 4; ++nt) {
          float h = acc[mt][nt][reg] + b1v[nt];
          h = h > 0.f ? h : 0.f;
          pacc = fmaf(h, w2v[nt], pacc);
        }
        v[mt][reg] = pacc;
      }
#pragma unroll
    for (int mask = 1; mask < 16; mask <<= 1)
#pragma unroll
      for (int mt = 0; mt < 4; ++mt)
#pragma unroll
        for (int reg = 0; reg < 4; ++reg)
          v[mt][reg] += __shfl_xor(v[mt][reg], mask);

    if (l15 == 0) {
#pragma unroll
      for (int mt = 0; mt < 4; ++mt)
#pragma unroll
        for (int reg = 0; reg < 4; ++reg)
          part[ng][mt * 16 + quad * 4 + reg] = v[mt][reg];
    }
  }
  __syncthreads();
  if (tid < 64)
    logits[m0 + tid] = (part[0][tid] + part[1][tid]) + b2[0];
}

// ---------------------------------------------------------------------------
// Row kernel: expected_k, k, gumbel, softmax. grid=8, block=1024. (unchanged)
// ---------------------------------------------------------------------------
__global__ __launch_bounds__(1024) void row_kernel(
    const float* __restrict__ logits, const float* __restrict__ u,
    float* __restrict__ soft, int* __restrict__ krow, float* __restrict__ ek_out)
{
  const int b = blockIdx.x;
  const int t = threadIdx.x;
  const float* Lrow = logits + b * S_;
  const float* urow = u + b * S_;

  __shared__ double red[1024];
  __shared__ float  redf[1024];

  float z[4];
  double psig = 0.0;
  float zmax = -INFINITY;
#pragma unroll
  for (int i = 0; i < 4; ++i) {
    int j = t + i * 1024;
    float L = Lrow[j];
    float g = -logf(-logf(urow[j]));
    z[i] = L + g;
    psig += (double)(1.f / (1.f + expf(-L)));
    zmax = fmaxf(zmax, z[i]);
  }
  red[t] = psig; redf[t] = zmax;
  __syncthreads();
  for (int s2 = 512; s2 > 0; s2 >>= 1) {
    if (t < s2) { red[t] += red[t + s2]; redf[t] = fmaxf(redf[t], redf[t + s2]); }
    __syncthreads();
  }
  __shared__ float m_sh; __shared__ double ek_sh;
  if (t == 0) { m_sh = redf[0]; ek_sh = red[0]; }
  __syncthreads();
  float m = m_sh;

  float e[4];
  double pexp = 0.0;
#pragma unroll
  for (int i = 0; i < 4; ++i) { e[i] = expf(z[i] - m); pexp += (double)e[i]; }
  red[t] = pexp;
  __syncthreads();
  for (int s2 = 512; s2 > 0; s2 >>= 1) {
    if (t < s2) red[t] += red[t + s2];
    __syncthreads();
  }
  __shared__ float den_sh;
  if (t == 0) den_sh = (float)red[0];
  __syncthreads();
  float den = den_sh;
#pragma unroll
  for (int i = 0; i < 4; ++i) soft[b * S_ + t + i * 1024] = e[i] / den;

  if (t == 0) {
    float ekf = (float)ek_sh;
    int k = (int)ekf;
    if (k < MIN_K) k = MIN_K;
    krow[b] = k;
    ek_out[b] = ekf;
  }
}

// ---------------------------------------------------------------------------
// Rank partial: grid (16 i-chunks, 4 j-chunks, 8 rows). Integer atomicAdd
// (deterministic). j-chunk staged in LDS; all lanes read same addr (broadcast).
// ---------------------------------------------------------------------------
__global__ __launch_bounds__(256) void rank_kernel(
    const float* __restrict__ soft, int* __restrict__ counts)
{
  __shared__ float4 sjs[256];
  const int b  = blockIdx.z;
  const int ic = blockIdx.x;
  const int jc = blockIdx.y;
  const int tid = threadIdx.x;
  const float* row = soft + b * S_;

  sjs[tid] = ((const float4*)row)[jc * 256 + tid];
  const int i = ic * 256 + tid;
  const float si = row[i];
  __syncthreads();

  int cnt = 0;
  const int jbase = jc * 1024;
  for (int j4 = 0; j4 < 256; ++j4) {
    float4 vv = sjs[j4];
    int j = jbase + j4 * 4;
    cnt += (vv.x > si) || (vv.x == si && (j + 0) < i);
    cnt += (vv.y > si) || (vv.y == si && (j + 1) < i);
    cnt += (vv.z > si) || (vv.z == si && (j + 2) < i);
    cnt += (vv.w > si) || (vv.w == si && (j + 3) < i);
  }
  atomicAdd(&counts[b * S_ + i], cnt);
}

// ---------------------------------------------------------------------------
// Filter + mask finalize: one block per token (1024 floats). Uniform scalar
// loads of cnt/k/soft; thread 0 writes selection_mask.
// ---------------------------------------------------------------------------
__global__ __launch_bounds__(256) void filter_kernel(
    const float* __restrict__ x, const float* __restrict__ soft,
    const int* __restrict__ counts, const int* __restrict__ krow,
    float* __restrict__ out, float* __restrict__ mask_out)
{
  const int token = blockIdx.x;           // 0..32767
  const int b = token >> 12;              // S_=4096
  const float s = soft[token];
  const float h = (counts[token] < krow[b]) ? 1.f : 0.f;
  const float sel = (h - s) + s;

  size_t base = (size_t)token * (E_ / 4) + threadIdx.x;
  float4 v = ((const float4*)x)[base];
  v.x *= sel; v.y *= sel; v.z *= sel; v.w *= sel;
  ((float4*)out)[base] = v;
  if (threadIdx.x == 0) mask_out[token] = sel;
}

// ---------------------------------------------------------------------------
extern "C" void kernel_launch(void* const* d_in, const int* in_sizes, int n_in,
                              void* d_out, int out_size, void* d_ws, size_t ws_size,
                              hipStream_t stream) {
  const float* x  = (const float*)d_in[0];
  const float* w1 = (const float*)d_in[1];
  const float* b1 = (const float*)d_in[2];
  const float* w2 = (const float*)d_in[3];
  const float* b2 = (const float*)d_in[4];
  const float* u  = (const float*)d_in[5];

  float* out = (float*)d_out;
  float* out_filt = out;
  float* out_mask = out + OUT_MASK_OFF;
  float* out_ek   = out + OUT_EK_OFF;

  char* ws = (char*)d_ws;
  float*          ws_logits = (float*)(ws + LOGITS_OFF);
  float*          ws_soft   = (float*)(ws + SOFT_OFF);
  int*            ws_cnt    = (int*)(ws + CNT_OFF);
  int*            ws_krow   = (int*)(ws + KROW_OFF);
  unsigned short* ws_wb     = (unsigned short*)(ws + WB_OFF);

  hipMemsetAsync(ws_cnt, 0, B_ * S_ * sizeof(int), stream);
  prep_w_kernel<<<dim3(128), dim3(256), 0, stream>>>(w1, ws_wb);
  scorer_kernel<<<dim3(B_ * S_ / 64), dim3(256), 0, stream>>>(
      x, ws_wb, b1, w2, b2, ws_logits);
  row_kernel<<<dim3(B_), dim3(1024), 0, stream>>>(ws_logits, u, ws_soft, ws_krow, out_ek);
  rank_kernel<<<dim3(16, 4, 8), dim3(256), 0, stream>>>(ws_soft, ws_cnt);
  filter_kernel<<<dim3(B_ * S_), dim3(256), 0, stream>>>(
      x, ws_soft, ws_cnt, ws_krow, out_filt, out_mask);
}